// Round 2
// baseline (97.095 us; speedup 1.0000x reference)
//
#include <hip/hip_runtime.h>

// Batched zero-phase Butterworth filtfilt (order 5), rows of length 8192.
// One block per row; chunked IIR with 64-step warmup (pole decay 0.819^64 ~ 3e-6).
// y (forward-filtered) lives only in LDS -> HBM traffic = read x + write out.

#define NN   8192     // row length
#define PADL 18       // filtfilt pad length
#define LC   32       // outputs per thread
#define WC   64       // warmup steps
#define TPB  256      // threads per block (NN / LC)
#define LDSZ (8210 + 257)   // y indices up to 8209, padded by j>>5

__device__ __forceinline__ int pidx(int j) { return j + (j >> 5); }

// one DF2T step; updates z0..z4, sets yv
#define STEP(xv) do {                         \
    float y_ = fmaf(b0, (xv), z0);            \
    z0 = fmaf(b1, (xv), z1) - a1 * y_;        \
    z1 = fmaf(b2, (xv), z2) - a2 * y_;        \
    z2 = fmaf(b3, (xv), z3) - a3 * y_;        \
    z3 = fmaf(b4, (xv), z4) - a4 * y_;        \
    z4 = fmaf(b5, (xv), -a5 * y_);            \
    yv = y_;                                  \
} while (0)

__global__ __launch_bounds__(TPB, 4) void GREEN_62869731278967_filtfilt(
    const float* __restrict__ x,
    const float* __restrict__ bc,
    const float* __restrict__ ac,
    const float* __restrict__ zc,
    float* __restrict__ out)
{
    __shared__ float lds[LDSZ];
    const int row = blockIdx.x;
    const int tid = threadIdx.x;
    const float* xr  = x   + (size_t)row * NN;
    float*       outr = out + (size_t)row * NN;

    const float b0 = bc[0], b1 = bc[1], b2 = bc[2], b3 = bc[3], b4 = bc[4], b5 = bc[5];
    const float a1 = ac[1], a2 = ac[2], a3 = ac[3], a4 = ac[4], a5 = ac[5];
    const float zi0 = zc[0], zi1 = zc[1], zi2 = zc[2], zi3 = zc[3], zi4 = zc[4];

    // ---- Phase A: stage x row into padded LDS (coalesced float4 loads) ----
#pragma unroll
    for (int q = 0; q < NN / (TPB * 4); ++q) {
        int i = (q * TPB + tid) * 4;
        float4 v = *reinterpret_cast<const float4*>(xr + i);
        lds[pidx(i + 0)] = v.x;
        lds[pidx(i + 1)] = v.y;
        lds[pidx(i + 2)] = v.z;
        lds[pidx(i + 3)] = v.w;
    }
    __syncthreads();

    const float x0 = lds[pidx(0)];
    const float xN = lds[pidx(NN - 1)];

    // ---- Phase B: forward filter; outputs y[t], t in [PADL+tid*LC, +LC) ----
    float yreg[LC];
    float ytail[PADL];   // only tid == TPB-1 uses
    {
        const int t0 = PADL + tid * LC - WC;
        float z0, z1, z2, z3, z4, yv;
        {
            // init = zi * ext[max(t0,0)]; feeding clamped const before t=0
            // keeps state exactly at steady value (DC gain 1) -> edge chunks exact.
            int tcl = t0 < 0 ? 0 : t0;
            int i1 = tcl - PADL;
            int j  = i1 < 0 ? -i1 : i1;
            float v = lds[pidx(j)];
            if (i1 < 0) v = 2.f * x0 - v;
            z0 = zi0 * v; z1 = zi1 * v; z2 = zi2 * v; z3 = zi3 * v; z4 = zi4 * v;
        }
        // warmup (left-reflection possible; right-reflection impossible here)
#pragma unroll 2
        for (int i = 0; i < WC; ++i) {
            int t = t0 + i;
            int tcl = t < 0 ? 0 : t;
            int i1 = tcl - PADL;
            int j  = i1 < 0 ? -i1 : i1;
            float v = lds[pidx(j)];
            if (i1 < 0) v = 2.f * x0 - v;
            STEP(v);
        }
        // outputs: ext index i1 = tid*LC + i, always in [0, NN)
#pragma unroll
        for (int i = 0; i < LC; ++i) {
            float v = lds[pidx(tid * LC + i)];
            STEP(v);
            yreg[i] = yv;
        }
        if (tid == TPB - 1) {
            // tail y[NN+PADL .. NN+2*PADL): ext = 2*xN - x[NN-2-i]
#pragma unroll
            for (int i = 0; i < PADL; ++i) {
                float v = 2.f * xN - lds[pidx(NN - 2 - i)];
                STEP(v);
                ytail[i] = yv;
            }
        }
    }
    __syncthreads();

    // ---- Phase C: write y back into LDS (y[t] at index t-PADL) ----
#pragma unroll
    for (int i = 0; i < LC; ++i) lds[pidx(tid * LC + i)] = yreg[i];
    if (tid == TPB - 1) {
#pragma unroll
        for (int i = 0; i < PADL; ++i) lds[pidx(NN + i)] = ytail[i];
    }
    __syncthreads();

    // ---- Phase D: backward filter; final[k] = y2[NN+PADL-1-k] ----
    {
        const int k0  = tid * LC;
        const int TOP = NN + PADL - 1;            // 8209
        const int s0  = NN + PADL - LC - k0 - WC; // first (pre-warmup) s
        float z0, z1, z2, z3, z4, yv;
        {
            int scl = s0 < 0 ? 0 : s0;
            float u0 = lds[pidx(TOP - scl)];
            z0 = zi0 * u0; z1 = zi1 * u0; z2 = zi2 * u0; z3 = zi3 * u0; z4 = zi4 * u0;
        }
#pragma unroll 2
        for (int i = 0; i < WC; ++i) {
            int s = s0 + i;
            int scl = s < 0 ? 0 : s;
            float v = lds[pidx(TOP - scl)];
            STEP(v);
        }
        float freg[LC];
#pragma unroll
        for (int i = 0; i < LC; ++i) {
            int s = s0 + WC + i;       // >= PADL, no clamp needed
            float v = lds[pidx(TOP - s)];
            STEP(v);
            freg[LC - 1 - i] = yv;     // k - k0 = LC-1-i
        }
#pragma unroll
        for (int q = 0; q < LC / 4; ++q) {
            float4 v;
            v.x = freg[4 * q + 0];
            v.y = freg[4 * q + 1];
            v.z = freg[4 * q + 2];
            v.w = freg[4 * q + 3];
            *reinterpret_cast<float4*>(outr + k0 + 4 * q) = v;
        }
    }
}

extern "C" void kernel_launch(void* const* d_in, const int* in_sizes, int n_in,
                              void* d_out, int out_size, void* d_ws, size_t ws_size,
                              hipStream_t stream) {
    const float* x  = (const float*)d_in[0];
    const float* b  = (const float*)d_in[1];
    const float* a  = (const float*)d_in[2];
    const float* zi = (const float*)d_in[3];
    float* out = (float*)d_out;
    const int rows = in_sizes[0] / NN;   // 4096
    GREEN_62869731278967_filtfilt<<<rows, TPB, 0, stream>>>(x, b, a, zi, out);
}

// Round 3
// 65.911 us; speedup vs baseline: 1.4731x; 1.4731x over previous
//
#include <hip/hip_runtime.h>

// Batched zero-phase Butterworth filtfilt (order 5), rows of length 8192.
// One block (256 thr) per row. Chunked IIR: each thread owns a 32-sample chunk,
// warms up over exactly the previous chunk (WC=32; pole decay 0.819^32 ~ 1.7e-3,
// test threshold 8.8e-2). Padded LDS layout idx(j) = (j>>5)*33 + (j&31) makes
// per-chunk access affine -> ds_read with immediate offsets, and stride-32
// lane access conflict-free. Edge chunks (tid 0 fwd / tid 255 bwd) take exact
// reference paths. y (forward result) lives only in LDS.

#define NN   8192
#define PADL 18
#define LC   32
#define WC   32          // == LC: warmup is exactly one chunk
#define TPB  256
#define CH   33          // padded chunk stride (floats)
#define LDSZ (256 * CH + PADL)   // 8466 floats = 33864 B

__device__ __forceinline__ int pidx(int j) { return j + (j >> 5); }  // == (j>>5)*CH + (j&31)

// one DF2T step; updates z0..z4, sets yv. 11 VALU ops (10 fma + 1 mul).
#define STEP(xv) do {                               \
    float y_ = fmaf(b0, (xv), z0);                  \
    z0 = fmaf(na1, y_, fmaf(b1, (xv), z1));         \
    z1 = fmaf(na2, y_, fmaf(b2, (xv), z2));         \
    z2 = fmaf(na3, y_, fmaf(b3, (xv), z3));         \
    z3 = fmaf(na4, y_, fmaf(b4, (xv), z4));         \
    z4 = fmaf(na5, y_, b5 * (xv));                  \
    yv = y_;                                        \
} while (0)

__global__ __launch_bounds__(TPB, 4) void GREEN_62869731278967_filtfilt(
    const float* __restrict__ x,
    const float* __restrict__ bc,
    const float* __restrict__ ac,
    const float* __restrict__ zc,
    float* __restrict__ out)
{
    __shared__ float lds[LDSZ];
    const int row = blockIdx.x;
    const int tid = threadIdx.x;
    const float* xr   = x   + (size_t)row * NN;
    float*       outr = out + (size_t)row * NN;

    const float b0 = bc[0], b1 = bc[1], b2 = bc[2], b3 = bc[3], b4 = bc[4], b5 = bc[5];
    const float na1 = -ac[1], na2 = -ac[2], na3 = -ac[3], na4 = -ac[4], na5 = -ac[5];
    const float zi0 = zc[0], zi1 = zc[1], zi2 = zc[2], zi3 = zc[3], zi4 = zc[4];

    // ---- Phase A: stage x row into padded LDS (coalesced float4 loads) ----
#pragma unroll
    for (int q = 0; q < NN / (TPB * 4); ++q) {
        int i = (q * TPB + tid) * 4;
        float4 v = *reinterpret_cast<const float4*>(xr + i);
        int p = pidx(i);            // i%4==0 -> i..i+3 stay in one chunk
        lds[p + 0] = v.x;
        lds[p + 1] = v.y;
        lds[p + 2] = v.z;
        lds[p + 3] = v.w;
    }
    __syncthreads();

    const float x0 = lds[0];
    const float xN = lds[pidx(NN - 1)];

    // ---- Phase B: forward filter; thread tid produces y[t], t in [PADL+tid*32, +32) ----
    float yreg[LC];
    float ytail[PADL];              // only tid == TPB-1 uses
    {
        float z0, z1, z2, z3, z4, yv;
        if (tid == 0) {
            // exact reference path: init zi*ext[0], feed the 18 reflected samples.
            // (the t<0 clamped steps are exact no-ops at steady state: DC gain 1)
            float v0 = 2.f * x0 - lds[pidx(PADL)];
            z0 = zi0 * v0; z1 = zi1 * v0; z2 = zi2 * v0; z3 = zi3 * v0; z4 = zi4 * v0;
#pragma unroll 3
            for (int t = 0; t < PADL; ++t) {
                float v = 2.f * x0 - lds[pidx(PADL - t)];
                STEP(v);
            }
        } else {
            // approximate: init zi*x[first], warm up over exactly chunk tid-1
            const float* p = &lds[(tid - 1) * CH];
            float v0 = p[0];
            z0 = zi0 * v0; z1 = zi1 * v0; z2 = zi2 * v0; z3 = zi3 * v0; z4 = zi4 * v0;
#pragma unroll 4
            for (int i = 0; i < WC; ++i) STEP(p[i]);
        }
        // outputs: chunk tid (affine, fully unrolled -> immediate-offset ds_reads)
        {
            const float* p = &lds[tid * CH];
#pragma unroll
            for (int i = 0; i < LC; ++i) { STEP(p[i]); yreg[i] = yv; }
        }
        if (tid == TPB - 1) {
            // tail y[NN+PADL .. NN+2*PADL): ext = 2*xN - x[NN-2-i]
#pragma unroll 3
            for (int i = 0; i < PADL; ++i) {
                float v = 2.f * xN - lds[pidx(NN - 2 - i)];
                STEP(v);
                ytail[i] = yv;
            }
        }
    }
    __syncthreads();

    // ---- Phase C: write y back into LDS (y[t] at chunk index t-PADL) ----
    {
        float* p = &lds[tid * CH];
#pragma unroll
        for (int i = 0; i < LC; ++i) p[i] = yreg[i];
    }
    if (tid == TPB - 1) {
#pragma unroll 3
        for (int i = 0; i < PADL; ++i) lds[256 * CH + i] = ytail[i];
    }
    __syncthreads();

    // ---- Phase D: backward filter over reversed y; final[k] = y2[8209-k] ----
    {
        float z0, z1, z2, z3, z4, yv;
        if (tid == TPB - 1) {
            // exact reference path: init zi*y[-1], feed the 18 tail samples descending
            float u0 = lds[256 * CH + PADL - 1];
            z0 = zi0 * u0; z1 = zi1 * u0; z2 = zi2 * u0; z3 = zi3 * u0; z4 = zi4 * u0;
#pragma unroll 3
            for (int s = 0; s < PADL; ++s) {
                float v = lds[256 * CH + PADL - 1 - s];
                STEP(v);
            }
        } else {
            // approximate: warm up over exactly chunk tid+1, descending
            const float* p = &lds[(tid + 1) * CH];
            float u0 = p[LC - 1];
            z0 = zi0 * u0; z1 = zi1 * u0; z2 = zi2 * u0; z3 = zi3 * u0; z4 = zi4 * u0;
#pragma unroll 4
            for (int i = 0; i < WC; ++i) STEP(p[LC - 1 - i]);
        }
        // outputs: chunk tid descending; output sample k = tid*32 + 31 - i
        float freg[LC];
        {
            const float* p = &lds[tid * CH];
#pragma unroll
            for (int i = 0; i < LC; ++i) { STEP(p[LC - 1 - i]); freg[LC - 1 - i] = yv; }
        }
#pragma unroll
        for (int q = 0; q < LC / 4; ++q) {
            float4 v;
            v.x = freg[4 * q + 0];
            v.y = freg[4 * q + 1];
            v.z = freg[4 * q + 2];
            v.w = freg[4 * q + 3];
            *reinterpret_cast<float4*>(outr + tid * LC + 4 * q) = v;
        }
    }
}

extern "C" void kernel_launch(void* const* d_in, const int* in_sizes, int n_in,
                              void* d_out, int out_size, void* d_ws, size_t ws_size,
                              hipStream_t stream) {
    const float* x  = (const float*)d_in[0];
    const float* b  = (const float*)d_in[1];
    const float* a  = (const float*)d_in[2];
    const float* zi = (const float*)d_in[3];
    float* out = (float*)d_out;
    const int rows = in_sizes[0] / NN;   // 4096
    GREEN_62869731278967_filtfilt<<<rows, TPB, 0, stream>>>(x, b, a, zi, out);
}

// Round 4
// 63.236 us; speedup vs baseline: 1.5354x; 1.0423x over previous
//
#include <hip/hip_runtime.h>

// Batched zero-phase Butterworth filtfilt (order 5), rows of length 8192.
// One block (256 thr) per row; each thread owns a 32-sample chunk and warms up
// over exactly the neighbor chunk (pole decay 0.819^32 ~ 1.7e-3 << 8.8e-2 thr).
// LDS: transposed + XOR-swizzled layout, element i of chunk c at word
//   xw(c,i) = i*256 + (c ^ (((i>>2)&7)<<2))
// -> exactly 8192 words = 32768 B (5 blocks/CU), all accesses <=2-way (free).
// Forward tail y[8210..8227] stays in tid 255's registers. Phase D consumes
// the thread's own forward output from registers (yreg), LDS only for warmup.

#define NN   8192
#define PADL 18
#define LC   32
#define TPB  256

__device__ __forceinline__ int xw(int c, int i) {
    return (i << 8) + (c ^ (((i >> 2) & 7) << 2));
}

// one DF2T step; updates z0..z4, sets yv (10 fma + 1 mul)
#define STEP(xv) do {                               \
    float y_ = fmaf(b0, (xv), z0);                  \
    z0 = fmaf(na1, y_, fmaf(b1, (xv), z1));         \
    z1 = fmaf(na2, y_, fmaf(b2, (xv), z2));         \
    z2 = fmaf(na3, y_, fmaf(b3, (xv), z3));         \
    z3 = fmaf(na4, y_, fmaf(b4, (xv), z4));         \
    z4 = fmaf(na5, y_, b5 * (xv));                  \
    yv = y_;                                        \
} while (0)

__global__ __launch_bounds__(TPB, 5) void GREEN_62869731278967_filtfilt(
    const float* __restrict__ x,
    const float* __restrict__ bc,
    const float* __restrict__ ac,
    const float* __restrict__ zc,
    float* __restrict__ out)
{
    __shared__ float lds[NN];            // 32768 B exactly
    const int row = blockIdx.x;
    const int tid = threadIdx.x;
    const float* xr   = x   + (size_t)row * NN;
    float*       outr = out + (size_t)row * NN;

    const float b0 = bc[0], b1 = bc[1], b2 = bc[2], b3 = bc[3], b4 = bc[4], b5 = bc[5];
    const float na1 = -ac[1], na2 = -ac[2], na3 = -ac[3], na4 = -ac[4], na5 = -ac[5];
    const float zi0 = zc[0], zi1 = zc[1], zi2 = zc[2], zi3 = zc[3], zi4 = zc[4];

    // ---- Phase A: coalesced float4 loads -> swizzled LDS ----
    // j = 1024q + 4t + m  =>  word = 1024(t&7) + 256m + 32q + ((t>>3)^((t&7)<<2))
    {
        const int Abase = ((tid & 7) << 10) + ((tid >> 3) ^ ((tid & 7) << 2));
#pragma unroll
        for (int q = 0; q < 8; ++q) {
            float4 v = *reinterpret_cast<const float4*>(xr + (q << 10) + (tid << 2));
            lds[Abase + (q << 5) + 0]   = v.x;
            lds[Abase + (q << 5) + 256] = v.y;
            lds[Abase + (q << 5) + 512] = v.z;
            lds[Abase + (q << 5) + 768] = v.w;
        }
    }
    __syncthreads();

    const float x0 = lds[xw(0, 0)];
    const float xN = lds[xw(255, 31)];

    // ---- Phase B: forward filter; thread tid produces y[t], t in [18+32*tid, +32) ----
    float yreg[LC];
    float ytail[PADL];                   // only tid == 255 uses
    {
        float z0, z1, z2, z3, z4, yv;
        if (tid == 0) {
            // exact reference path: init zi*ext[0], feed the 18 reflected samples
            float v0 = 2.f * x0 - lds[xw(0, PADL)];
            z0 = zi0 * v0; z1 = zi1 * v0; z2 = zi2 * v0; z3 = zi3 * v0; z4 = zi4 * v0;
#pragma unroll
            for (int t = 0; t < PADL; ++t) {
                float v = 2.f * x0 - lds[xw(0, PADL - t)];
                STEP(v);
            }
        } else {
            // approximate: init zi*x[first], warm up over exactly chunk tid-1
            const int cp = tid - 1;
            float v0 = lds[xw(cp, 0)];
            z0 = zi0 * v0; z1 = zi1 * v0; z2 = zi2 * v0; z3 = zi3 * v0; z4 = zi4 * v0;
#pragma unroll
            for (int i = 0; i < LC; ++i) STEP(lds[xw(cp, i)]);
        }
        // outputs: own chunk (immediate-offset ds_reads off 8 CSE'd bases)
#pragma unroll
        for (int i = 0; i < LC; ++i) { STEP(lds[xw(tid, i)]); yreg[i] = yv; }
        if (tid == TPB - 1) {
            // tail y[8210..8227): ext = 2*xN - x[8190-i]  (chunk 255, elem 30-i)
#pragma unroll
            for (int i = 0; i < PADL; ++i) {
                float v = 2.f * xN - lds[xw(255, 30 - i)];
                STEP(v);
                ytail[i] = yv;
            }
        }
    }
    __syncthreads();

    // ---- Phase C: overwrite LDS chunk tid with y (same swizzled addresses) ----
#pragma unroll
    for (int i = 0; i < LC; ++i) lds[xw(tid, i)] = yreg[i];
    __syncthreads();

    // ---- Phase D: backward filter over reversed y; own chunk comes from yreg ----
    {
        float z0, z1, z2, z3, z4, yv;
        if (tid == TPB - 1) {
            // exact reference path: init zi*y_last, feed 18 tail samples descending
            float u0 = ytail[PADL - 1];
            z0 = zi0 * u0; z1 = zi1 * u0; z2 = zi2 * u0; z3 = zi3 * u0; z4 = zi4 * u0;
#pragma unroll
            for (int s = 0; s < PADL; ++s) STEP(ytail[PADL - 1 - s]);
        } else {
            // approximate: warm up over exactly chunk tid+1, descending
            const int cn = tid + 1;
            float u0 = lds[xw(cn, LC - 1)];
            z0 = zi0 * u0; z1 = zi1 * u0; z2 = zi2 * u0; z3 = zi3 * u0; z4 = zi4 * u0;
#pragma unroll
            for (int i = 0; i < LC; ++i) STEP(lds[xw(cn, LC - 1 - i)]);
        }
        // outputs: own chunk descending, straight from registers
        float freg[LC];
#pragma unroll
        for (int i = 0; i < LC; ++i) { STEP(yreg[LC - 1 - i]); freg[LC - 1 - i] = yv; }
#pragma unroll
        for (int q = 0; q < LC / 4; ++q) {
            float4 v;
            v.x = freg[4 * q + 0];
            v.y = freg[4 * q + 1];
            v.z = freg[4 * q + 2];
            v.w = freg[4 * q + 3];
            *reinterpret_cast<float4*>(outr + tid * LC + 4 * q) = v;
        }
    }
}

extern "C" void kernel_launch(void* const* d_in, const int* in_sizes, int n_in,
                              void* d_out, int out_size, void* d_ws, size_t ws_size,
                              hipStream_t stream) {
    const float* x  = (const float*)d_in[0];
    const float* b  = (const float*)d_in[1];
    const float* a  = (const float*)d_in[2];
    const float* zi = (const float*)d_in[3];
    float* out = (float*)d_out;
    const int rows = in_sizes[0] / NN;   // 4096
    GREEN_62869731278967_filtfilt<<<rows, TPB, 0, stream>>>(x, b, a, zi, out);
}